// Round 1
// baseline (246.554 us; speedup 1.0000x reference)
//
#include <hip/hip_runtime.h>

#define N_NODES_C   524288
#define N_EDGES_C   786432
#define NUM_GRAPHS_C 8192
#define NT 16          // NUM_NODE_TYPES
#define NODE_DIM_C 256
#define EDGE_DIM_C 128
#define HDIM 384       // NODE_DIM + EDGE_DIM

// ---------------- workspace layout (bytes) ----------------
// sn   : int[8193]            @ 0
// se   : int[8193]            @ 65536
// nm   : float[8192*16]       @ 131072      (node mean, 16-dim)
// em   : float[8192*32]       @ 655360      (edge mean, 32-dim)
// hsub : float[8192*384]      @ 1703936
#define WS_SN    0
#define WS_SE    65536
#define WS_NM    131072
#define WS_EM    655360
#define WS_HSUB  1703936

__device__ __forceinline__ int lower_bound_i32(const int* __restrict__ a, int n, int key) {
    int lo = 0, hi = n;
    while (lo < hi) {
        int mid = (lo + hi) >> 1;
        if (a[mid] < key) lo = mid + 1; else hi = mid;
    }
    return lo;
}

// K0: per-graph start offsets for nodes and edges (sorted batch arrays)
__global__ void k0_starts(const int* __restrict__ bnode, const int* __restrict__ bedge,
                          int* __restrict__ sn, int* __restrict__ se) {
    int t = blockIdx.x * blockDim.x + threadIdx.x;
    if (t < NUM_GRAPHS_C + 1) {
        sn[t] = lower_bound_i32(bnode, N_NODES_C, t);
    } else if (t < 2 * (NUM_GRAPHS_C + 1)) {
        int g = t - (NUM_GRAPHS_C + 1);
        se[g] = lower_bound_i32(bedge, N_EDGES_C, g);
    }
}

// K1: node segment means over raw 16-dim features. 16 graphs x 16 dims per 256-thread block.
__global__ void k1_node_mean(const float* __restrict__ h_node, const int* __restrict__ sn,
                             float* __restrict__ nm) {
    int d = threadIdx.x & 15;
    int g = blockIdx.x * (blockDim.x >> 4) + (threadIdx.x >> 4);
    if (g >= NUM_GRAPHS_C) return;
    int s = sn[g], e = sn[g + 1];
    float acc0 = 0.f, acc1 = 0.f;
    int i = s;
    for (; i + 2 <= e; i += 2) {
        acc0 += h_node[i * NT + d];
        acc1 += h_node[(i + 1) * NT + d];
    }
    if (i < e) acc0 += h_node[i * NT + d];
    float cnt = (float)(e - s);
    nm[g * NT + d] = (acc0 + acc1) / fmaxf(cnt, 1.f);
}

// K2: edge segment means over cat(h[src], h[dst]) (32-dim). 8 graphs x 32 dims per block.
__global__ void k2_edge_mean(const float* __restrict__ h_node,
                             const int* __restrict__ esrc, const int* __restrict__ edst,
                             const int* __restrict__ se, float* __restrict__ em) {
    int d = threadIdx.x & 31;
    int g = blockIdx.x * (blockDim.x >> 5) + (threadIdx.x >> 5);
    if (g >= NUM_GRAPHS_C) return;
    const int* __restrict__ idxp = (d < 16) ? esrc : edst;
    int dd = d & 15;
    int s = se[g], e = se[g + 1];
    float acc0 = 0.f, acc1 = 0.f;
    int i = s;
    for (; i + 2 <= e; i += 2) {
        int i0 = idxp[i];
        int i1 = idxp[i + 1];
        acc0 += h_node[i0 * NT + dd];
        acc1 += h_node[i1 * NT + dd];
    }
    if (i < e) acc0 += h_node[idxp[i] * NT + dd];
    float cnt = (float)(e - s);
    em[g * 32 + d] = (acc0 + acc1) / fmaxf(cnt, 1.f);
}

// K3: build h_sub[g][384] = cat(nm @ W_node, em @ W_edge). One block (384 threads) per graph.
__global__ void k3_hsub(const float* __restrict__ nm, const float* __restrict__ em,
                        const float* __restrict__ Wn, const float* __restrict__ We,
                        float* __restrict__ hsub) {
    int g = blockIdx.x;
    int j = threadIdx.x;   // 0..383
    __shared__ float s_nm[NT];
    __shared__ float s_em[32];
    if (j < NT) s_nm[j] = nm[g * NT + j];
    else if (j < NT + 32) s_em[j - NT] = em[g * 32 + (j - NT)];
    __syncthreads();
    float acc = 0.f;
    if (j < NODE_DIM_C) {
        #pragma unroll
        for (int k = 0; k < NT; ++k) acc = fmaf(s_nm[k], Wn[k * NODE_DIM_C + j], acc);
    } else {
        int jj = j - NODE_DIM_C;
        #pragma unroll
        for (int k = 0; k < 32; ++k) acc = fmaf(s_em[k], We[k * EDGE_DIM_C + jj], acc);
    }
    hsub[g * HDIM + j] = acc;
}

// K4: fused MLP: pred[g] = sum_j relu( hsub[g]·W1[:,j] + b1[j] ) * W2[j] + b2
// 32 graphs per 256-thread block; K staged in LDS chunks of 16; 4x12 register tile.
#define MT 32
#define KB 16
__global__ __launch_bounds__(256) void k4_mlp(
    const float* __restrict__ hsub, const float* __restrict__ W1,
    const float* __restrict__ b1,  const float* __restrict__ W2,
    const float* __restrict__ b2,  float* __restrict__ pred) {
    __shared__ float As[MT * KB];       // [g][k]  2 KB
    __shared__ float Ws[KB * HDIM];     // [k][j]  24 KB
    int tid = threadIdx.x;
    int tj  = tid & 31;                 // j lane: j = tj + 32*jj
    int tg  = tid >> 5;                 // 0..7: owns graphs tg*4 .. tg*4+3
    int gblock = blockIdx.x * MT;

    float acc[4][12];
    #pragma unroll
    for (int i = 0; i < 4; ++i)
        #pragma unroll
        for (int jj = 0; jj < 12; ++jj) acc[i][jj] = 0.f;

    for (int k0 = 0; k0 < HDIM; k0 += KB) {
        // stage A tile: MT*KB = 512 floats, 2 consecutive per thread
        {
            int idx = tid * 2;
            int g = idx >> 4;           // /KB
            int k = idx & (KB - 1);
            const float* src = &hsub[(size_t)(gblock + g) * HDIM + k0 + k];
            As[idx]     = src[0];
            As[idx + 1] = src[1];
        }
        // stage W tile: rows k0..k0+15 of W1 are contiguous (row-major): 6144 floats
        {
            const float4* w4  = (const float4*)(&W1[(size_t)k0 * HDIM]);
            float4* ws4 = (float4*)Ws;
            #pragma unroll
            for (int r = 0; r < 6; ++r) ws4[tid + 256 * r] = w4[tid + 256 * r];
        }
        __syncthreads();
        #pragma unroll
        for (int kk = 0; kk < KB; ++kk) {
            float a[4], w[12];
            #pragma unroll
            for (int i = 0; i < 4; ++i) a[i] = As[(tg * 4 + i) * KB + kk];
            #pragma unroll
            for (int jj = 0; jj < 12; ++jj) w[jj] = Ws[kk * HDIM + tj + 32 * jj];
            #pragma unroll
            for (int i = 0; i < 4; ++i)
                #pragma unroll
                for (int jj = 0; jj < 12; ++jj) acc[i][jj] = fmaf(a[i], w[jj], acc[i][jj]);
        }
        __syncthreads();
    }

    // epilogue: bias + relu + dot with W2, reduce over j (width-32 shuffle)
    float b1r[12], w2r[12];
    #pragma unroll
    for (int jj = 0; jj < 12; ++jj) {
        int j = tj + 32 * jj;
        b1r[jj] = b1[j];
        w2r[jj] = W2[j];
    }
    float bias2 = b2[0];
    #pragma unroll
    for (int i = 0; i < 4; ++i) {
        float p = 0.f;
        #pragma unroll
        for (int jj = 0; jj < 12; ++jj) {
            float z = acc[i][jj] + b1r[jj];
            z = fmaxf(z, 0.f);
            p = fmaf(z, w2r[jj], p);
        }
        #pragma unroll
        for (int off = 16; off > 0; off >>= 1) p += __shfl_down(p, off, 32);
        if (tj == 0) pred[gblock + tg * 4 + i] = p + bias2;
    }
}

extern "C" void kernel_launch(void* const* d_in, const int* in_sizes, int n_in,
                              void* d_out, int out_size, void* d_ws, size_t ws_size,
                              hipStream_t stream) {
    const float* h_node    = (const float*)d_in[0];
    // d_in[1] = pos_node (unused by reference)
    const int*   batch_node = (const int*)d_in[2];
    const int*   edge_index = (const int*)d_in[3];   // [2, E] row-major
    const int*   batch_edge = (const int*)d_in[4];
    const float* W_node    = (const float*)d_in[5];
    const float* W_edge    = (const float*)d_in[6];
    const float* W1        = (const float*)d_in[7];
    const float* b1        = (const float*)d_in[8];
    const float* W2        = (const float*)d_in[9];
    const float* b2        = (const float*)d_in[10];
    float* pred = (float*)d_out;

    char* ws = (char*)d_ws;
    int*   sn   = (int*)(ws + WS_SN);
    int*   se   = (int*)(ws + WS_SE);
    float* nm   = (float*)(ws + WS_NM);
    float* em   = (float*)(ws + WS_EM);
    float* hsub = (float*)(ws + WS_HSUB);

    const int* esrc = edge_index;
    const int* edst = edge_index + N_EDGES_C;

    // K0: graph start offsets
    {
        int total = 2 * (NUM_GRAPHS_C + 1);
        int blocks = (total + 255) / 256;
        k0_starts<<<blocks, 256, 0, stream>>>(batch_node, batch_edge, sn, se);
    }
    // K1: node means (16 graphs / block)
    k1_node_mean<<<NUM_GRAPHS_C / 16, 256, 0, stream>>>(h_node, sn, nm);
    // K2: edge means (8 graphs / block)
    k2_edge_mean<<<NUM_GRAPHS_C / 8, 256, 0, stream>>>(h_node, esrc, edst, se, em);
    // K3: h_sub
    k3_hsub<<<NUM_GRAPHS_C, HDIM, 0, stream>>>(nm, em, W_node, W_edge, hsub);
    // K4: fused MLP
    k4_mlp<<<NUM_GRAPHS_C / MT, 256, 0, stream>>>(hsub, W1, b1, W2, b2, pred);
}

// Round 2
// 175.744 us; speedup vs baseline: 1.4029x; 1.4029x over previous
//
#include <hip/hip_runtime.h>

#define N_NODES_C   524288
#define N_EDGES_C   786432
#define NUM_GRAPHS_C 8192
#define NT 16          // NUM_NODE_TYPES
#define NODE_DIM_C 256
#define EDGE_DIM_C 128
#define HDIM 384       // NODE_DIM + EDGE_DIM
#define KC 48          // folded inner dim: 16 (node) + 32 (edge)

// ---------------- workspace layout (bytes) ----------------
#define WS_SN    0                  // int[8193]
#define WS_SE    65536              // int[8193]
#define WS_NM    131072             // float[8192*16]
#define WS_EM    655360             // float[8192*32]
#define WS_WC    1703936            // float[48*384]

__device__ __forceinline__ int lower_bound_i32(const int* __restrict__ a, int n, int key) {
    int lo = 0, hi = n;
    while (lo < hi) {
        int mid = (lo + hi) >> 1;
        if (a[mid] < key) lo = mid + 1; else hi = mid;
    }
    return lo;
}

// K0: per-graph start offsets (batch arrays are sorted)
__global__ void k0_starts(const int* __restrict__ bnode, const int* __restrict__ bedge,
                          int* __restrict__ sn, int* __restrict__ se) {
    int t = blockIdx.x * blockDim.x + threadIdx.x;
    if (t < NUM_GRAPHS_C + 1) {
        sn[t] = lower_bound_i32(bnode, N_NODES_C, t);
    } else if (t < 2 * (NUM_GRAPHS_C + 1)) {
        int g = t - (NUM_GRAPHS_C + 1);
        se[g] = lower_bound_i32(bedge, N_EDGES_C, g);
    }
}

// KW: fold embedders into W1.  Wc[k][j]:
//   k<16 :  Wn[k,:](256) . W1[0:256, j]
//   k>=16:  We[k-16,:](128) . W1[256:384, j]
__global__ __launch_bounds__(HDIM) void kw_fold(
    const float* __restrict__ Wn, const float* __restrict__ We,
    const float* __restrict__ W1, float* __restrict__ Wc) {
    int k = blockIdx.x;   // 0..47
    int j = threadIdx.x;  // 0..383
    float acc = 0.f;
    if (k < NT) {
        const float* wr = &Wn[k * NODE_DIM_C];
        for (int kk = 0; kk < NODE_DIM_C; ++kk)
            acc = fmaf(wr[kk], W1[(size_t)kk * HDIM + j], acc);
    } else {
        const float* wr = &We[(k - NT) * EDGE_DIM_C];
        for (int kk = 0; kk < EDGE_DIM_C; ++kk)
            acc = fmaf(wr[kk], W1[(size_t)(NODE_DIM_C + kk) * HDIM + j], acc);
    }
    Wc[k * HDIM + j] = acc;
}

__device__ __forceinline__ void f4_shfl_xor_add(float4& a, int mask) {
    a.x += __shfl_xor(a.x, mask, 64);
    a.y += __shfl_xor(a.y, mask, 64);
    a.z += __shfl_xor(a.z, mask, 64);
    a.w += __shfl_xor(a.w, mask, 64);
}

// K1: node segment means, wave per graph, float4 fully-coalesced (1 KB / wave-instr).
// lane = row_off*4 + quad : 16 rows x 4 quads per iteration.
__global__ __launch_bounds__(256) void k1_node_mean(
    const float* __restrict__ h_node, const int* __restrict__ sn,
    float* __restrict__ nm) {
    int wave = threadIdx.x >> 6;
    int lane = threadIdx.x & 63;
    int g = blockIdx.x * 4 + wave;
    int s = sn[g], e = sn[g + 1];
    int row_off = lane >> 2;   // 0..15
    int quad    = lane & 3;    // 0..3
    const float4* h4 = (const float4*)h_node;
    float4 acc = make_float4(0.f, 0.f, 0.f, 0.f);
    for (int i = s + row_off; i < e; i += 16) {
        float4 v = h4[(size_t)i * 4 + quad];
        acc.x += v.x; acc.y += v.y; acc.z += v.z; acc.w += v.w;
    }
    // reduce over row_off (lane bits 2..5)
    f4_shfl_xor_add(acc, 4);
    f4_shfl_xor_add(acc, 8);
    f4_shfl_xor_add(acc, 16);
    f4_shfl_xor_add(acc, 32);
    if (row_off == 0) {
        float inv = 1.f / fmaxf((float)(e - s), 1.f);
        float4 r = make_float4(acc.x * inv, acc.y * inv, acc.z * inv, acc.w * inv);
        ((float4*)nm)[(size_t)g * 4 + quad] = r;
    }
}

// K2: edge segment means, wave per graph, 8 edges / iteration.
// lane = e_off*8 + p*4 + quad ; 4-lane (quad) groups fetch one 64 B row.
__global__ __launch_bounds__(256) void k2_edge_mean(
    const float* __restrict__ h_node,
    const int* __restrict__ esrc, const int* __restrict__ edst,
    const int* __restrict__ se, float* __restrict__ em) {
    int wave = threadIdx.x >> 6;
    int lane = threadIdx.x & 63;
    int g = blockIdx.x * 4 + wave;
    int s = se[g], e = se[g + 1];
    int e_off = lane >> 3;          // 0..7
    int p     = (lane >> 2) & 1;    // 0=src 1=dst
    int quad  = lane & 3;           // 0..3
    const int* __restrict__ idxp = p ? edst : esrc;
    const float4* h4 = (const float4*)h_node;
    float4 acc = make_float4(0.f, 0.f, 0.f, 0.f);
    for (int i = s + e_off; i < e; i += 8) {
        int idx = idxp[i];
        float4 v = h4[(size_t)idx * 4 + quad];
        acc.x += v.x; acc.y += v.y; acc.z += v.z; acc.w += v.w;
    }
    // reduce over e_off (lane bits 3..5)
    f4_shfl_xor_add(acc, 8);
    f4_shfl_xor_add(acc, 16);
    f4_shfl_xor_add(acc, 32);
    if (e_off == 0) {
        float inv = 1.f / fmaxf((float)(e - s), 1.f);
        float4 r = make_float4(acc.x * inv, acc.y * inv, acc.z * inv, acc.w * inv);
        // em row = 32 floats: quads 0..3 = src half, 4..7 = dst half
        ((float4*)em)[(size_t)g * 8 + p * 4 + quad] = r;
    }
}

// K3: fused MLP.  pred[g] = relu(f[g] @ Wc + b1) . W2 + b2,  f = [nm | em] (48)
// 384 threads (thread owns column j of Wc in registers), 16 graphs / block.
#define GPB 16
__global__ __launch_bounds__(HDIM) void k3_mlp(
    const float* __restrict__ nm, const float* __restrict__ em,
    const float* __restrict__ Wc, const float* __restrict__ b1,
    const float* __restrict__ W2, const float* __restrict__ b2,
    float* __restrict__ pred) {
    int j = threadIdx.x;
    float wc[KC];
    #pragma unroll
    for (int k = 0; k < KC; ++k) wc[k] = Wc[k * HDIM + j];
    float b1j = b1[j], w2j = W2[j], b20 = b2[0];

    __shared__ float fs[GPB][KC];
    __shared__ float part[GPB][6];
    int g0 = blockIdx.x * GPB;
    #pragma unroll
    for (int t = j; t < GPB * KC; t += HDIM) {
        int g = t / KC, k = t % KC;
        fs[g][k] = (k < NT) ? nm[(size_t)(g0 + g) * NT + k]
                            : em[(size_t)(g0 + g) * 32 + (k - NT)];
    }
    __syncthreads();

    int wave = j >> 6, lane = j & 63;
    for (int g = 0; g < GPB; ++g) {
        float z = b1j;
        #pragma unroll
        for (int k = 0; k < KC; ++k) z = fmaf(fs[g][k], wc[k], z);
        z = fmaxf(z, 0.f);
        float p = z * w2j;
        #pragma unroll
        for (int off = 32; off > 0; off >>= 1) p += __shfl_down(p, off, 64);
        if (lane == 0) part[g][wave] = p;
    }
    __syncthreads();
    if (j < GPB) {
        float sacc = b20;
        #pragma unroll
        for (int w = 0; w < 6; ++w) sacc += part[j][w];
        pred[g0 + j] = sacc;
    }
}

extern "C" void kernel_launch(void* const* d_in, const int* in_sizes, int n_in,
                              void* d_out, int out_size, void* d_ws, size_t ws_size,
                              hipStream_t stream) {
    const float* h_node     = (const float*)d_in[0];
    // d_in[1] = pos_node (unused)
    const int*   batch_node = (const int*)d_in[2];
    const int*   edge_index = (const int*)d_in[3];   // [2, E] row-major
    const int*   batch_edge = (const int*)d_in[4];
    const float* W_node     = (const float*)d_in[5];
    const float* W_edge     = (const float*)d_in[6];
    const float* W1         = (const float*)d_in[7];
    const float* b1         = (const float*)d_in[8];
    const float* W2         = (const float*)d_in[9];
    const float* b2         = (const float*)d_in[10];
    float* pred = (float*)d_out;

    char* ws = (char*)d_ws;
    int*   sn = (int*)(ws + WS_SN);
    int*   se = (int*)(ws + WS_SE);
    float* nm = (float*)(ws + WS_NM);
    float* em = (float*)(ws + WS_EM);
    float* Wc = (float*)(ws + WS_WC);

    const int* esrc = edge_index;
    const int* edst = edge_index + N_EDGES_C;

    // KW: fold W_node/W_edge into W1 (independent of K0 results)
    kw_fold<<<KC, HDIM, 0, stream>>>(W_node, W_edge, W1, Wc);
    // K0: graph start offsets
    {
        int total = 2 * (NUM_GRAPHS_C + 1);
        k0_starts<<<(total + 255) / 256, 256, 0, stream>>>(batch_node, batch_edge, sn, se);
    }
    // K1: node means — wave per graph, 4 graphs/block
    k1_node_mean<<<NUM_GRAPHS_C / 4, 256, 0, stream>>>(h_node, sn, nm);
    // K2: edge means — wave per graph, 4 graphs/block
    k2_edge_mean<<<NUM_GRAPHS_C / 4, 256, 0, stream>>>(h_node, esrc, edst, se, em);
    // K3: fused folded MLP
    k3_mlp<<<NUM_GRAPHS_C / GPB, HDIM, 0, stream>>>(nm, em, Wc, b1, W2, b2, pred);
}

// Round 4
// 161.832 us; speedup vs baseline: 1.5235x; 1.0860x over previous
//
#include <hip/hip_runtime.h>

#define N_NODES_C   524288
#define N_EDGES_C   786432
#define NUM_GRAPHS_C 8192
#define NT 16          // NUM_NODE_TYPES
#define NODE_DIM_C 256
#define EDGE_DIM_C 128
#define HDIM 384       // NODE_DIM + EDGE_DIM
#define KC 48          // folded inner dim: 16 (node) + 32 (edge)

// blocks needed for the 2*(G+1)=16386 binary searches, at 256 thr/block
#define START_BLOCKS 65
#define FOLD_BLOCKS  72    // ceil(KC*HDIM / 256) = 18432/256

// ---------------- workspace layout (bytes) ----------------
#define WS_SN    0                  // int[8193]
#define WS_SE    65536              // int[8193]
#define WS_NM    131072             // float[8192*16]
#define WS_EM    655360             // float[8192*32]
#define WS_WC    1703936            // float[48*384]

__device__ __forceinline__ int lower_bound_i32(const int* __restrict__ a, int n, int key) {
    int lo = 0, hi = n;
    while (lo < hi) {
        int mid = (lo + hi) >> 1;
        if (a[mid] < key) lo = mid + 1; else hi = mid;
    }
    return lo;
}

// KP: fused prep. blocks [0,START_BLOCKS): segment start offsets (binary search,
// sorted batch arrays — 16386 searches). blocks [START_BLOCKS, +FOLD_BLOCKS):
// folded weight Wc[k][j] = embedder_row(k) . W1 block.
__global__ __launch_bounds__(256) void kp_prep(
    const int* __restrict__ bnode, const int* __restrict__ bedge,
    const float* __restrict__ Wn, const float* __restrict__ We,
    const float* __restrict__ W1,
    int* __restrict__ sn, int* __restrict__ se, float* __restrict__ Wc) {
    int blk = blockIdx.x;
    if (blk < START_BLOCKS) {
        int t = blk * 256 + threadIdx.x;
        if (t < NUM_GRAPHS_C + 1) {
            sn[t] = lower_bound_i32(bnode, N_NODES_C, t);
        } else if (t < 2 * (NUM_GRAPHS_C + 1)) {
            se[t - (NUM_GRAPHS_C + 1)] = lower_bound_i32(bedge, N_EDGES_C, t - (NUM_GRAPHS_C + 1));
        }
    } else {
        int o = (blk - START_BLOCKS) * 256 + threadIdx.x;   // 0..18431 (= KC*HDIM)
        if (o >= KC * HDIM) return;
        int k = o / HDIM, j = o % HDIM;
        float acc = 0.f;
        if (k < NT) {
            const float* wr = &Wn[k * NODE_DIM_C];
            #pragma unroll 4
            for (int kk = 0; kk < NODE_DIM_C; ++kk)
                acc = fmaf(wr[kk], W1[(size_t)kk * HDIM + j], acc);
        } else {
            const float* wr = &We[(k - NT) * EDGE_DIM_C];
            #pragma unroll 4
            for (int kk = 0; kk < EDGE_DIM_C; ++kk)
                acc = fmaf(wr[kk], W1[(size_t)(NODE_DIM_C + kk) * HDIM + j], acc);
        }
        Wc[o] = acc;
    }
}

__device__ __forceinline__ void f4_shfl_xor_add(float4& a, int mask) {
    a.x += __shfl_xor(a.x, mask, 64);
    a.y += __shfl_xor(a.y, mask, 64);
    a.z += __shfl_xor(a.z, mask, 64);
    a.w += __shfl_xor(a.w, mask, 64);
}

// KM: fused segment means, wave per graph.
// blocks [0,2048): node means — lane = row_off*4+quad, 16 rows x 4 quads / iter,
//   float4 fully-coalesced (1 KB per wave-instruction).
// blocks [2048,4096): edge means — lane = e_off*8 + p*4 + quad, 8 edges / iter,
//   2-way unrolled for independent idx->gather chains.
__global__ __launch_bounds__(256) void km_means(
    const float* __restrict__ h_node, const int* __restrict__ sn,
    const int* __restrict__ se,
    const int* __restrict__ esrc, const int* __restrict__ edst,
    float* __restrict__ nm, float* __restrict__ em) {
    int wave = threadIdx.x >> 6;
    int lane = threadIdx.x & 63;
    const float4* h4 = (const float4*)h_node;

    if (blockIdx.x < 2048) {
        int g = blockIdx.x * 4 + wave;
        int s = sn[g], e = sn[g + 1];
        int row_off = lane >> 2;   // 0..15
        int quad    = lane & 3;    // 0..3
        float4 acc = make_float4(0.f, 0.f, 0.f, 0.f);
        for (int i = s + row_off; i < e; i += 16) {
            float4 v = h4[(size_t)i * 4 + quad];
            acc.x += v.x; acc.y += v.y; acc.z += v.z; acc.w += v.w;
        }
        f4_shfl_xor_add(acc, 4);
        f4_shfl_xor_add(acc, 8);
        f4_shfl_xor_add(acc, 16);
        f4_shfl_xor_add(acc, 32);
        if (row_off == 0) {
            float inv = 1.f / fmaxf((float)(e - s), 1.f);
            ((float4*)nm)[(size_t)g * 4 + quad] =
                make_float4(acc.x * inv, acc.y * inv, acc.z * inv, acc.w * inv);
        }
    } else {
        int g = (blockIdx.x - 2048) * 4 + wave;
        int s = se[g], e = se[g + 1];
        int e_off = lane >> 3;          // 0..7
        int p     = (lane >> 2) & 1;    // 0=src 1=dst
        int quad  = lane & 3;           // 0..3
        const int* __restrict__ idxp = p ? edst : esrc;
        float4 acc0 = make_float4(0.f, 0.f, 0.f, 0.f);
        float4 acc1 = make_float4(0.f, 0.f, 0.f, 0.f);
        int i = s + e_off;
        for (; i + 8 < e; i += 16) {
            int ia = idxp[i];
            int ib = idxp[i + 8];
            float4 va = h4[(size_t)ia * 4 + quad];
            float4 vb = h4[(size_t)ib * 4 + quad];
            acc0.x += va.x; acc0.y += va.y; acc0.z += va.z; acc0.w += va.w;
            acc1.x += vb.x; acc1.y += vb.y; acc1.z += vb.z; acc1.w += vb.w;
        }
        if (i < e) {
            float4 v = h4[(size_t)idxp[i] * 4 + quad];
            acc0.x += v.x; acc0.y += v.y; acc0.z += v.z; acc0.w += v.w;
        }
        acc0.x += acc1.x; acc0.y += acc1.y; acc0.z += acc1.z; acc0.w += acc1.w;
        f4_shfl_xor_add(acc0, 8);
        f4_shfl_xor_add(acc0, 16);
        f4_shfl_xor_add(acc0, 32);
        if (e_off == 0) {
            float inv = 1.f / fmaxf((float)(e - s), 1.f);
            // em row = 32 floats: quads 0..3 = src half, 4..7 = dst half
            ((float4*)em)[(size_t)g * 8 + p * 4 + quad] =
                make_float4(acc0.x * inv, acc0.y * inv, acc0.z * inv, acc0.w * inv);
        }
    }
}

// K3: fused MLP.  pred[g] = relu(f[g] @ Wc + b1) . W2 + b2,  f = [nm | em] (48)
// 384 threads (thread owns column j of Wc in registers), 16 graphs / block.
#define GPB 16
__global__ __launch_bounds__(HDIM) void k3_mlp(
    const float* __restrict__ nm, const float* __restrict__ em,
    const float* __restrict__ Wc, const float* __restrict__ b1,
    const float* __restrict__ W2, const float* __restrict__ b2,
    float* __restrict__ pred) {
    int j = threadIdx.x;
    float wc[KC];
    #pragma unroll
    for (int k = 0; k < KC; ++k) wc[k] = Wc[k * HDIM + j];
    float b1j = b1[j], w2j = W2[j], b20 = b2[0];

    __shared__ float fs[GPB][KC];
    __shared__ float part[GPB][6];
    int g0 = blockIdx.x * GPB;
    #pragma unroll
    for (int t = j; t < GPB * KC; t += HDIM) {
        int g = t / KC, k = t % KC;
        fs[g][k] = (k < NT) ? nm[(size_t)(g0 + g) * NT + k]
                            : em[(size_t)(g0 + g) * 32 + (k - NT)];
    }
    __syncthreads();

    int wave = j >> 6, lane = j & 63;
    for (int g = 0; g < GPB; ++g) {
        float z = b1j;
        #pragma unroll
        for (int k = 0; k < KC; ++k) z = fmaf(fs[g][k], wc[k], z);
        z = fmaxf(z, 0.f);
        float p = z * w2j;
        #pragma unroll
        for (int off = 32; off > 0; off >>= 1) p += __shfl_down(p, off, 64);
        if (lane == 0) part[g][wave] = p;
    }
    __syncthreads();
    if (j < GPB) {
        float sacc = b20;
        #pragma unroll
        for (int w = 0; w < 6; ++w) sacc += part[j][w];
        pred[g0 + j] = sacc;
    }
}

extern "C" void kernel_launch(void* const* d_in, const int* in_sizes, int n_in,
                              void* d_out, int out_size, void* d_ws, size_t ws_size,
                              hipStream_t stream) {
    const float* h_node     = (const float*)d_in[0];
    // d_in[1] = pos_node (unused)
    const int*   batch_node = (const int*)d_in[2];
    const int*   edge_index = (const int*)d_in[3];   // [2, E] row-major
    const int*   batch_edge = (const int*)d_in[4];
    const float* W_node     = (const float*)d_in[5];
    const float* W_edge     = (const float*)d_in[6];
    const float* W1         = (const float*)d_in[7];
    const float* b1         = (const float*)d_in[8];
    const float* W2         = (const float*)d_in[9];
    const float* b2         = (const float*)d_in[10];
    float* pred = (float*)d_out;

    char* ws = (char*)d_ws;
    int*   sn = (int*)(ws + WS_SN);
    int*   se = (int*)(ws + WS_SE);
    float* nm = (float*)(ws + WS_NM);
    float* em = (float*)(ws + WS_EM);
    float* Wc = (float*)(ws + WS_WC);

    const int* esrc = edge_index;
    const int* edst = edge_index + N_EDGES_C;

    // KP: starts (65 blocks: 16386 searches) + folded weights (72 blocks)
    kp_prep<<<START_BLOCKS + FOLD_BLOCKS, 256, 0, stream>>>(
        batch_node, batch_edge, W_node, W_edge, W1, sn, se, Wc);
    // KM: node means (2048 blocks) + edge means (2048 blocks), wave per graph
    km_means<<<4096, 256, 0, stream>>>(h_node, sn, se, esrc, edst, nm, em);
    // K3: fused folded MLP
    k3_mlp<<<NUM_GRAPHS_C / GPB, HDIM, 0, stream>>>(nm, em, Wc, b1, W2, b2, pred);
}

// Round 5
// 148.543 us; speedup vs baseline: 1.6598x; 1.0895x over previous
//
#include <hip/hip_runtime.h>

#define N_NODES_C   524288
#define N_EDGES_C   786432
#define NUM_GRAPHS_C 8192
#define NT 16          // NUM_NODE_TYPES
#define NODE_DIM_C 256
#define EDGE_DIM_C 128
#define HDIM 384       // NODE_DIM + EDGE_DIM
#define KC 48          // folded inner dim: 16 (node) + 32 (edge)

// blocks needed for the 2*(G+1)=16386 binary searches, at 256 thr/block
#define START_BLOCKS 65
#define FOLD_BLOCKS  72    // ceil(KC*HDIM / 256) = 18432/256

// ---------------- workspace layout (bytes) ----------------
#define WS_SN    0                  // int[8193]
#define WS_SE    65536              // int[8193]
#define WS_NM    131072             // float[8192*16]
#define WS_EM    655360             // float[8192*32]
#define WS_WC    1703936            // float[48*384]

__device__ __forceinline__ int lower_bound_i32(const int* __restrict__ a, int n, int key) {
    int lo = 0, hi = n;
    while (lo < hi) {
        int mid = (lo + hi) >> 1;
        if (a[mid] < key) lo = mid + 1; else hi = mid;
    }
    return lo;
}

// KP: fused prep. blocks [0,START_BLOCKS): segment start offsets (binary search,
// sorted batch arrays — 16386 searches). blocks [START_BLOCKS, +FOLD_BLOCKS):
// folded weight Wc[k][j] = embedder_row(k) . W1 block.  unroll 16 => 16
// outstanding coalesced loads per wave instead of 4 (latency-bound loop).
__global__ __launch_bounds__(256) void kp_prep(
    const int* __restrict__ bnode, const int* __restrict__ bedge,
    const float* __restrict__ Wn, const float* __restrict__ We,
    const float* __restrict__ W1,
    int* __restrict__ sn, int* __restrict__ se, float* __restrict__ Wc) {
    int blk = blockIdx.x;
    if (blk < START_BLOCKS) {
        int t = blk * 256 + threadIdx.x;
        if (t < NUM_GRAPHS_C + 1) {
            sn[t] = lower_bound_i32(bnode, N_NODES_C, t);
        } else if (t < 2 * (NUM_GRAPHS_C + 1)) {
            se[t - (NUM_GRAPHS_C + 1)] = lower_bound_i32(bedge, N_EDGES_C, t - (NUM_GRAPHS_C + 1));
        }
    } else {
        int o = (blk - START_BLOCKS) * 256 + threadIdx.x;   // 0..18431 (= KC*HDIM)
        if (o >= KC * HDIM) return;
        int k = o / HDIM, j = o % HDIM;
        float acc = 0.f;
        if (k < NT) {
            const float* wr = &Wn[k * NODE_DIM_C];
            #pragma unroll 16
            for (int kk = 0; kk < NODE_DIM_C; ++kk)
                acc = fmaf(wr[kk], W1[(size_t)kk * HDIM + j], acc);
        } else {
            const float* wr = &We[(k - NT) * EDGE_DIM_C];
            #pragma unroll 16
            for (int kk = 0; kk < EDGE_DIM_C; ++kk)
                acc = fmaf(wr[kk], W1[(size_t)(NODE_DIM_C + kk) * HDIM + j], acc);
        }
        Wc[o] = acc;
    }
}

__device__ __forceinline__ void f4_shfl_xor_add(float4& a, int mask) {
    a.x += __shfl_xor(a.x, mask, 64);
    a.y += __shfl_xor(a.y, mask, 64);
    a.z += __shfl_xor(a.z, mask, 64);
    a.w += __shfl_xor(a.w, mask, 64);
}

// KM: fused segment means, wave per graph.
// blocks [0,2048): EDGE means (dispatched first — the long tail).
//   lane = p*32 + sl: each lane owns edge endpoints i = s+sl, s+sl+32, ...
//   per trip: 1 idx load + 4 independent float4 loads (full 64 B row per lane).
//   32 edges per wave-trip, 5 outstanding loads per lane per trip.
//   5-step butterfly within each 32-lane half at the end.
// blocks [2048,4096): NODE means — lane = row_off*4+quad, 16 rows x 4 quads /
//   iter, float4 fully-coalesced (1 KB per wave-instruction).
__global__ __launch_bounds__(256) void km_means(
    const float* __restrict__ h_node, const int* __restrict__ sn,
    const int* __restrict__ se,
    const int* __restrict__ esrc, const int* __restrict__ edst,
    float* __restrict__ nm, float* __restrict__ em) {
    int wave = threadIdx.x >> 6;
    int lane = threadIdx.x & 63;
    const float4* h4 = (const float4*)h_node;

    if (blockIdx.x < 2048) {
        // ---- edge means ----
        int g = blockIdx.x * 4 + wave;
        int s = se[g], e = se[g + 1];
        int p  = lane >> 5;             // 0 = src, 1 = dst
        int sl = lane & 31;
        const int* __restrict__ idxp = p ? edst : esrc;
        float4 a0 = make_float4(0.f, 0.f, 0.f, 0.f);
        float4 a1 = a0, a2 = a0, a3 = a0;
        for (int i = s + sl; i < e; i += 32) {
            const float4* row = h4 + (size_t)idxp[i] * 4;
            float4 v0 = row[0], v1 = row[1], v2 = row[2], v3 = row[3];
            a0.x += v0.x; a0.y += v0.y; a0.z += v0.z; a0.w += v0.w;
            a1.x += v1.x; a1.y += v1.y; a1.z += v1.z; a1.w += v1.w;
            a2.x += v2.x; a2.y += v2.y; a2.z += v2.z; a2.w += v2.w;
            a3.x += v3.x; a3.y += v3.y; a3.z += v3.z; a3.w += v3.w;
        }
        #pragma unroll
        for (int mask = 1; mask < 32; mask <<= 1) {
            f4_shfl_xor_add(a0, mask);
            f4_shfl_xor_add(a1, mask);
            f4_shfl_xor_add(a2, mask);
            f4_shfl_xor_add(a3, mask);
        }
        if (sl == 0) {
            float inv = 1.f / fmaxf((float)(e - s), 1.f);
            float4* emo = ((float4*)em) + (size_t)g * 8 + p * 4;  // [src 16 | dst 16]
            emo[0] = make_float4(a0.x * inv, a0.y * inv, a0.z * inv, a0.w * inv);
            emo[1] = make_float4(a1.x * inv, a1.y * inv, a1.z * inv, a1.w * inv);
            emo[2] = make_float4(a2.x * inv, a2.y * inv, a2.z * inv, a2.w * inv);
            emo[3] = make_float4(a3.x * inv, a3.y * inv, a3.z * inv, a3.w * inv);
        }
    } else {
        // ---- node means ----
        int g = (blockIdx.x - 2048) * 4 + wave;
        int s = sn[g], e = sn[g + 1];
        int row_off = lane >> 2;   // 0..15
        int quad    = lane & 3;    // 0..3
        float4 acc = make_float4(0.f, 0.f, 0.f, 0.f);
        for (int i = s + row_off; i < e; i += 16) {
            float4 v = h4[(size_t)i * 4 + quad];
            acc.x += v.x; acc.y += v.y; acc.z += v.z; acc.w += v.w;
        }
        f4_shfl_xor_add(acc, 4);
        f4_shfl_xor_add(acc, 8);
        f4_shfl_xor_add(acc, 16);
        f4_shfl_xor_add(acc, 32);
        if (row_off == 0) {
            float inv = 1.f / fmaxf((float)(e - s), 1.f);
            ((float4*)nm)[(size_t)g * 4 + quad] =
                make_float4(acc.x * inv, acc.y * inv, acc.z * inv, acc.w * inv);
        }
    }
}

// K3: fused MLP.  pred[g] = relu(f[g] @ Wc + b1) . W2 + b2,  f = [nm | em] (48)
// 384 threads (thread owns column j of Wc in registers), 16 graphs / block.
#define GPB 16
__global__ __launch_bounds__(HDIM) void k3_mlp(
    const float* __restrict__ nm, const float* __restrict__ em,
    const float* __restrict__ Wc, const float* __restrict__ b1,
    const float* __restrict__ W2, const float* __restrict__ b2,
    float* __restrict__ pred) {
    int j = threadIdx.x;
    float wc[KC];
    #pragma unroll
    for (int k = 0; k < KC; ++k) wc[k] = Wc[k * HDIM + j];
    float b1j = b1[j], w2j = W2[j], b20 = b2[0];

    __shared__ float fs[GPB][KC];
    __shared__ float part[GPB][6];
    int g0 = blockIdx.x * GPB;
    #pragma unroll
    for (int t = j; t < GPB * KC; t += HDIM) {
        int g = t / KC, k = t % KC;
        fs[g][k] = (k < NT) ? nm[(size_t)(g0 + g) * NT + k]
                            : em[(size_t)(g0 + g) * 32 + (k - NT)];
    }
    __syncthreads();

    int wave = j >> 6, lane = j & 63;
    for (int g = 0; g < GPB; ++g) {
        float z = b1j;
        #pragma unroll
        for (int k = 0; k < KC; ++k) z = fmaf(fs[g][k], wc[k], z);
        z = fmaxf(z, 0.f);
        float p = z * w2j;
        #pragma unroll
        for (int off = 32; off > 0; off >>= 1) p += __shfl_down(p, off, 64);
        if (lane == 0) part[g][wave] = p;
    }
    __syncthreads();
    if (j < GPB) {
        float sacc = b20;
        #pragma unroll
        for (int w = 0; w < 6; ++w) sacc += part[j][w];
        pred[g0 + j] = sacc;
    }
}

extern "C" void kernel_launch(void* const* d_in, const int* in_sizes, int n_in,
                              void* d_out, int out_size, void* d_ws, size_t ws_size,
                              hipStream_t stream) {
    const float* h_node     = (const float*)d_in[0];
    // d_in[1] = pos_node (unused)
    const int*   batch_node = (const int*)d_in[2];
    const int*   edge_index = (const int*)d_in[3];   // [2, E] row-major
    const int*   batch_edge = (const int*)d_in[4];
    const float* W_node     = (const float*)d_in[5];
    const float* W_edge     = (const float*)d_in[6];
    const float* W1         = (const float*)d_in[7];
    const float* b1         = (const float*)d_in[8];
    const float* W2         = (const float*)d_in[9];
    const float* b2         = (const float*)d_in[10];
    float* pred = (float*)d_out;

    char* ws = (char*)d_ws;
    int*   sn = (int*)(ws + WS_SN);
    int*   se = (int*)(ws + WS_SE);
    float* nm = (float*)(ws + WS_NM);
    float* em = (float*)(ws + WS_EM);
    float* Wc = (float*)(ws + WS_WC);

    const int* esrc = edge_index;
    const int* edst = edge_index + N_EDGES_C;

    // KP: starts (65 blocks: 16386 searches) + folded weights (72 blocks)
    kp_prep<<<START_BLOCKS + FOLD_BLOCKS, 256, 0, stream>>>(
        batch_node, batch_edge, W_node, W_edge, W1, sn, se, Wc);
    // KM: edge means (2048 blocks, first) + node means (2048 blocks), wave/graph
    km_means<<<4096, 256, 0, stream>>>(h_node, sn, se, esrc, edst, nm, em);
    // K3: fused folded MLP
    k3_mlp<<<NUM_GRAPHS_C / GPB, HDIM, 0, stream>>>(nm, em, Wc, b1, W2, b2, pred);
}

// Round 6
// 148.419 us; speedup vs baseline: 1.6612x; 1.0008x over previous
//
#include <hip/hip_runtime.h>

#define N_NODES_C   524288
#define N_EDGES_C   786432
#define NUM_GRAPHS_C 8192
#define NT 16          // NUM_NODE_TYPES
#define NODE_DIM_C 256
#define EDGE_DIM_C 128
#define HDIM 384       // NODE_DIM + EDGE_DIM
#define KC 48          // folded inner dim: 16 (node) + 32 (edge)

#define FOLD_BLOCKS  72            // ceil(KC*HDIM / 256)
#define EDGE_BLOCKS  2048          // 4 waves/block, wave per graph
#define NODE_BLOCKS  2048
#define EDGE_BASE    FOLD_BLOCKS
#define NODE_BASE    (FOLD_BLOCKS + EDGE_BLOCKS)
#define TOTAL_BLOCKS (FOLD_BLOCKS + EDGE_BLOCKS + NODE_BLOCKS)

// ---------------- workspace layout (bytes) ----------------
#define WS_NM    0                  // float[8192*16]   (node means)
#define WS_EM    524288             // float[8192*32]   (edge means)
#define WS_WC    1572864            // float[48*384]    (folded weights)

__device__ __forceinline__ int lower_bound_i32(const int* __restrict__ a, int n, int key) {
    int lo = 0, hi = n;
    while (lo < hi) {
        int mid = (lo + hi) >> 1;
        if (a[mid] < key) lo = mid + 1; else hi = mid;
    }
    return lo;
}

// In-wave segment bounds: lanes 0-31 chase start(g), lanes 32-63 chase end(g)
// concurrently (identical addresses within each half broadcast in the memory
// system), then shuffle-broadcast. ~20 dependent L2-hit steps, hidden by TLP.
__device__ __forceinline__ void wave_seg_bounds(const int* __restrict__ b, int n,
                                                int g, int lane, int& s, int& e) {
    int key = g + ((lane >= 32) ? 1 : 0);
    int lo = lower_bound_i32(b, n, key);
    s = __shfl(lo, 0, 64);
    e = __shfl(lo, 32, 64);
}

__device__ __forceinline__ void f4_shfl_xor_add(float4& a, int mask) {
    a.x += __shfl_xor(a.x, mask, 64);
    a.y += __shfl_xor(a.y, mask, 64);
    a.z += __shfl_xor(a.z, mask, 64);
    a.w += __shfl_xor(a.w, mask, 64);
}

// KM mega-kernel:
//  blocks [0,FOLD_BLOCKS):     Wc[k][j] = embedder_row(k) . W1 block (unroll 16)
//  blocks [EDGE_BASE,+2048):   edge means, wave/graph, in-wave bounds search.
//     lane = eo(0..7)*8 + p*4 + quad: quad shares a 64-B row (16 lines/instr),
//     two pipelined chains (i, i+8; stride 16) w/ 1-deep index prefetch.
//  blocks [NODE_BASE,+2048):   node means, wave/graph, fully-coalesced float4.
__global__ __launch_bounds__(256) void km_mega(
    const float* __restrict__ h_node,
    const int* __restrict__ bnode, const int* __restrict__ bedge,
    const int* __restrict__ esrc, const int* __restrict__ edst,
    const float* __restrict__ Wn, const float* __restrict__ We,
    const float* __restrict__ W1,
    float* __restrict__ nm, float* __restrict__ em, float* __restrict__ Wc) {
    int blk  = blockIdx.x;
    int wave = threadIdx.x >> 6;
    int lane = threadIdx.x & 63;
    const float4* h4 = (const float4*)h_node;

    if (blk < FOLD_BLOCKS) {
        // ---- weight fold ----
        int o = blk * 256 + threadIdx.x;        // 0..18431 (= KC*HDIM)
        if (o >= KC * HDIM) return;
        int k = o / HDIM, j = o % HDIM;
        float acc = 0.f;
        if (k < NT) {
            const float* wr = &Wn[k * NODE_DIM_C];
            #pragma unroll 16
            for (int kk = 0; kk < NODE_DIM_C; ++kk)
                acc = fmaf(wr[kk], W1[(size_t)kk * HDIM + j], acc);
        } else {
            const float* wr = &We[(k - NT) * EDGE_DIM_C];
            #pragma unroll 16
            for (int kk = 0; kk < EDGE_DIM_C; ++kk)
                acc = fmaf(wr[kk], W1[(size_t)(NODE_DIM_C + kk) * HDIM + j], acc);
        }
        Wc[o] = acc;
    } else if (blk < NODE_BASE) {
        // ---- edge means ----
        int g = (blk - EDGE_BASE) * 4 + wave;
        int s, e;
        wave_seg_bounds(bedge, N_EDGES_C, g, lane, s, e);
        int eo   = lane >> 3;          // 0..7 edge slot
        int p    = (lane >> 2) & 1;    // 0=src 1=dst
        int quad = lane & 3;           // 16 B quarter of the 64-B row
        const int* __restrict__ idxp = p ? edst : esrc;
        float4 accA = make_float4(0.f, 0.f, 0.f, 0.f);
        float4 accB = accA;
        int iA = s + eo, iB = s + eo + 8;
        int nxA = (iA < e) ? idxp[iA] : -1;
        int nxB = (iB < e) ? idxp[iB] : -1;
        while (nxB >= 0) {             // nxB valid implies nxA valid (iA < iB)
            int idxA = nxA, idxB = nxB;
            iA += 16; iB += 16;
            nxA = (iA < e) ? idxp[iA] : -1;   // prefetch next pair (independent)
            nxB = (iB < e) ? idxp[iB] : -1;
            float4 va = h4[(size_t)idxA * 4 + quad];
            float4 vb = h4[(size_t)idxB * 4 + quad];
            accA.x += va.x; accA.y += va.y; accA.z += va.z; accA.w += va.w;
            accB.x += vb.x; accB.y += vb.y; accB.z += vb.z; accB.w += vb.w;
        }
        if (nxA >= 0) {                // at most one pending A element
            float4 v = h4[(size_t)nxA * 4 + quad];
            accA.x += v.x; accA.y += v.y; accA.z += v.z; accA.w += v.w;
        }
        accA.x += accB.x; accA.y += accB.y; accA.z += accB.z; accA.w += accB.w;
        // reduce over eo (lane bits 3..5)
        f4_shfl_xor_add(accA, 8);
        f4_shfl_xor_add(accA, 16);
        f4_shfl_xor_add(accA, 32);
        if (eo == 0) {
            float inv = 1.f / fmaxf((float)(e - s), 1.f);
            // em row = 32 floats: quads 0..3 = src half, 4..7 = dst half
            ((float4*)em)[(size_t)g * 8 + p * 4 + quad] =
                make_float4(accA.x * inv, accA.y * inv, accA.z * inv, accA.w * inv);
        }
    } else {
        // ---- node means ----
        int g = (blk - NODE_BASE) * 4 + wave;
        int s, e;
        wave_seg_bounds(bnode, N_NODES_C, g, lane, s, e);
        int row_off = lane >> 2;   // 0..15
        int quad    = lane & 3;    // 0..3
        float4 acc = make_float4(0.f, 0.f, 0.f, 0.f);
        for (int i = s + row_off; i < e; i += 16) {
            float4 v = h4[(size_t)i * 4 + quad];
            acc.x += v.x; acc.y += v.y; acc.z += v.z; acc.w += v.w;
        }
        f4_shfl_xor_add(acc, 4);
        f4_shfl_xor_add(acc, 8);
        f4_shfl_xor_add(acc, 16);
        f4_shfl_xor_add(acc, 32);
        if (row_off == 0) {
            float inv = 1.f / fmaxf((float)(e - s), 1.f);
            ((float4*)nm)[(size_t)g * 4 + quad] =
                make_float4(acc.x * inv, acc.y * inv, acc.z * inv, acc.w * inv);
        }
    }
}

// K3: fused MLP.  pred[g] = relu(f[g] @ Wc + b1) . W2 + b2,  f = [nm | em] (48)
// 384 threads (thread owns column j of Wc in registers), 16 graphs / block.
#define GPB 16
__global__ __launch_bounds__(HDIM) void k3_mlp(
    const float* __restrict__ nm, const float* __restrict__ em,
    const float* __restrict__ Wc, const float* __restrict__ b1,
    const float* __restrict__ W2, const float* __restrict__ b2,
    float* __restrict__ pred) {
    int j = threadIdx.x;
    float wc[KC];
    #pragma unroll
    for (int k = 0; k < KC; ++k) wc[k] = Wc[k * HDIM + j];
    float b1j = b1[j], w2j = W2[j], b20 = b2[0];

    __shared__ float fs[GPB][KC];
    __shared__ float part[GPB][6];
    int g0 = blockIdx.x * GPB;
    #pragma unroll
    for (int t = j; t < GPB * KC; t += HDIM) {
        int g = t / KC, k = t % KC;
        fs[g][k] = (k < NT) ? nm[(size_t)(g0 + g) * NT + k]
                            : em[(size_t)(g0 + g) * 32 + (k - NT)];
    }
    __syncthreads();

    int wave = j >> 6, lane = j & 63;
    for (int g = 0; g < GPB; ++g) {
        float z = b1j;
        #pragma unroll
        for (int k = 0; k < KC; ++k) z = fmaf(fs[g][k], wc[k], z);
        z = fmaxf(z, 0.f);
        float p = z * w2j;
        #pragma unroll
        for (int off = 32; off > 0; off >>= 1) p += __shfl_down(p, off, 64);
        if (lane == 0) part[g][wave] = p;
    }
    __syncthreads();
    if (j < GPB) {
        float sacc = b20;
        #pragma unroll
        for (int w = 0; w < 6; ++w) sacc += part[j][w];
        pred[g0 + j] = sacc;
    }
}

extern "C" void kernel_launch(void* const* d_in, const int* in_sizes, int n_in,
                              void* d_out, int out_size, void* d_ws, size_t ws_size,
                              hipStream_t stream) {
    const float* h_node     = (const float*)d_in[0];
    // d_in[1] = pos_node (unused)
    const int*   batch_node = (const int*)d_in[2];
    const int*   edge_index = (const int*)d_in[3];   // [2, E] row-major
    const int*   batch_edge = (const int*)d_in[4];
    const float* W_node     = (const float*)d_in[5];
    const float* W_edge     = (const float*)d_in[6];
    const float* W1         = (const float*)d_in[7];
    const float* b1         = (const float*)d_in[8];
    const float* W2         = (const float*)d_in[9];
    const float* b2         = (const float*)d_in[10];
    float* pred = (float*)d_out;

    char* ws = (char*)d_ws;
    float* nm = (float*)(ws + WS_NM);
    float* em = (float*)(ws + WS_EM);
    float* Wc = (float*)(ws + WS_WC);

    const int* esrc = edge_index;
    const int* edst = edge_index + N_EDGES_C;

    // KM: fold (72) + edge means (2048) + node means (2048); bounds searched in-wave
    km_mega<<<TOTAL_BLOCKS, 256, 0, stream>>>(
        h_node, batch_node, batch_edge, esrc, edst, W_node, W_edge, W1, nm, em, Wc);
    // K3: fused folded MLP
    k3_mlp<<<NUM_GRAPHS_C / GPB, HDIM, 0, stream>>>(nm, em, Wc, b1, W2, b2, pred);
}